// Round 6
// baseline (813.368 us; speedup 1.0000x reference)
//
#include <hip/hip_runtime.h>
#include <hip/hip_bf16.h>

#define N_PTS  (4096 * 192)
#define NT     4            // point-tiles (of 16) per wave -> 64 points/wave
#define NBLK   256          // persistent blocks, 1 per CU
#define NCHUNK (N_PTS / 512)

typedef __bf16 bf16x8 __attribute__((ext_vector_type(8)));
typedef float  f32x4  __attribute__((ext_vector_type(4)));
typedef float  f32x2  __attribute__((ext_vector_type(2)));

// LDS weight image (bf16 element offsets). Main tiles [m][k'] with k rows
// permuted by kinv (MFMA C-layout of layer l == B-frag layout of layer l+1)
// and column-chunk XOR-swizzled (16B slot s -> s ^ (m&15)) so ds_read_b128 at
// 256B row stride is bank-conflict-free (read applies the same XOR).
#define W1P 0          // 128x128
#define W2P 16384      // 128x128 (rows 0..127 of w2)
#define W3P 32768      // 128x128
#define WFP 49152      // 128x128
#define WRP 65536      // 64x128
#define W0E 73728      // 128x16  fixup vs pos-frag (natural f rows, k16 space)
#define W2E 75776      // 128x16
#define WRE 77824      // 64x16
#define WDE 78848      // 2x128   row0 = wd_hi[kinv], row1 = wd_lo[kinv]
#define WOE 79104      // 8x64    rows0-2 = wo_hi ch, rows4-6 = wo_lo ch
#define WS_ELEMS 79616 // 159,232 B  (fits 160 KiB LDS)

__device__ __forceinline__ int kinv(int k) {
  int c = k >> 5, q = (k >> 3) & 3, h = (k >> 2) & 1, r = k & 3;
  return (2 * c + h) * 16 + q * 4 + r;
}

__device__ __forceinline__ bf16x8 zero8() {
  bf16x8 z;
#pragma unroll
  for (int i = 0; i < 8; ++i) z[i] = (__bf16)0.f;
  return z;
}

__device__ __forceinline__ bf16x8 pack_relu(f32x4 e, f32x4 o) {
  bf16x8 v;
#pragma unroll
  for (int r = 0; r < 4; ++r) {
    v[r]     = (__bf16)fmaxf(e[r], 0.f);
    v[4 + r] = (__bf16)fmaxf(o[r], 0.f);
  }
  return v;
}

// One layer from LDS-resident swizzled weights. K=128, acts in registers.
template <int NPAIR, bool FIX>
__device__ __forceinline__ void mlayer(const __bf16* __restrict__ wlds,
                                       const float* __restrict__ bias,
                                       const __bf16* __restrict__ wext,
                                       const bf16x8 (&pf)[NT],
                                       const bf16x8 (&hin)[4][NT],
                                       bf16x8 (&hout)[NPAIR][NT],
                                       int l16, int quad) {
#pragma unroll
  for (int pr = 0; pr < NPAIR; ++pr) {
    f32x4 acc0[NT], acc1[NT];
    f32x4 bv0 = *(const f32x4*)(bias + pr * 32 + quad * 4);
    f32x4 bv1 = *(const f32x4*)(bias + pr * 32 + 16 + quad * 4);
#pragma unroll
    for (int nt = 0; nt < NT; ++nt) { acc0[nt] = bv0; acc1[nt] = bv1; }
#pragma unroll
    for (int c = 0; c < 4; ++c) {
      int chunk = ((c * 4 + quad) ^ l16) << 3;           // swizzled column chunk
      bf16x8 a0 = *(const bf16x8*)(wlds + (pr * 32 + l16) * 128 + chunk);
      bf16x8 a1 = *(const bf16x8*)(wlds + (pr * 32 + 16 + l16) * 128 + chunk);
#pragma unroll
      for (int nt = 0; nt < NT; ++nt) {
        acc0[nt] = __builtin_amdgcn_mfma_f32_16x16x32_bf16(a0, hin[c][nt], acc0[nt], 0, 0, 0);
        acc1[nt] = __builtin_amdgcn_mfma_f32_16x16x32_bf16(a1, hin[c][nt], acc1[nt], 0, 0, 0);
      }
    }
    if constexpr (FIX) {
      bf16x8 a0 = zero8(), a1 = zero8();
      if (quad < 2) {
        a0 = *(const bf16x8*)(wext + (pr * 32 + l16) * 16 + quad * 8);
        a1 = *(const bf16x8*)(wext + (pr * 32 + 16 + l16) * 16 + quad * 8);
      }
#pragma unroll
      for (int nt = 0; nt < NT; ++nt) {
        acc0[nt] = __builtin_amdgcn_mfma_f32_16x16x32_bf16(a0, pf[nt], acc0[nt], 0, 0, 0);
        acc1[nt] = __builtin_amdgcn_mfma_f32_16x16x32_bf16(a1, pf[nt], acc1[nt], 0, 0, 0);
      }
    }
#pragma unroll
    for (int nt = 0; nt < NT; ++nt) hout[pr][nt] = pack_relu(acc0[nt], acc1[nt]);
  }
}

__global__ __launch_bounds__(512, 1) void nerf_kernel(
    const float* __restrict__ x,
    const float* __restrict__ w0, const float* __restrict__ b0,
    const float* __restrict__ w1, const float* __restrict__ b1,
    const float* __restrict__ w2, const float* __restrict__ b2,
    const float* __restrict__ w3, const float* __restrict__ b3,
    const float* __restrict__ wd, const float* __restrict__ bd,
    const float* __restrict__ wf, const float* __restrict__ bfv,
    const float* __restrict__ wr, const float* __restrict__ br,
    const float* __restrict__ wo, const float* __restrict__ bo,
    float* __restrict__ out) {
  __shared__ __align__(16) __bf16 wsl[WS_ELEMS];   // 159,232 B — whole network

  const int tid  = threadIdx.x;
  const int wv   = tid >> 6;
  const int lane = tid & 63;
  const int quad = lane >> 4;
  const int l16  = lane & 15;
  const int pw   = wv * 64;

  // ---- one-time: build prepped weight image in LDS (same math as old prep)
  for (int i = tid; i < WS_ELEMS; i += 512) {
    if (i < 65536) {                     // w1,w2,w3,wf: k-permuted + swizzled
      int t = i >> 14, j = i & 16383, m = j >> 7, col = j & 127;
      int k = (((col >> 3) ^ (m & 15)) << 3) | (col & 7);
      int p = kinv(k);
      const float* wsel = (t == 0) ? w1 : (t == 1) ? w2 : (t == 2) ? w3 : wf;
      wsl[i] = (__bf16)wsel[p * 128 + m];
    } else if (i < 73728) {              // wr main tile
      int j = i - 65536, m = j >> 7, col = j & 127;
      int k = (((col >> 3) ^ (m & 15)) << 3) | (col & 7);
      wsl[i] = (__bf16)wr[kinv(k) * 64 + m];
    } else if (i < 75776) {              // W0E
      int j = i - 73728, f = j >> 4, k = j & 15; float v = 0.f;
      if (k < 3)      v = w0[k * 128 + f];
      else if (k < 6) v = w0[(k - 3) * 128 + f];
      else if (k < 9) { float ww = w0[(k - 6) * 128 + f]; v = ww - (float)(__bf16)ww; }
      wsl[i] = (__bf16)v;
    } else if (i < 77824) {              // W2E
      int j = i - 75776, f = j >> 4, k = j & 15; float v = 0.f;
      if (k < 3)      v = w2[(128 + k) * 128 + f];
      else if (k < 6) v = w2[(128 + k - 3) * 128 + f];
      else if (k < 9) { float ww = w2[(128 + k - 6) * 128 + f]; v = ww - (float)(__bf16)ww; }
      wsl[i] = (__bf16)v;
    } else if (i < 78848) {              // WRE
      int j = i - 77824, n = j >> 4, k = j & 15; float v = 0.f;
      if (k >= 9 && k < 15) v = wr[(128 + ((k - 9) % 3)) * 64 + n];
      wsl[i] = (__bf16)v;
    } else if (i < 79104) {              // WDE: wd hi/lo, k-permuted
      int j = i - 78848, drow = j >> 7, k = j & 127, p = kinv(k);
      float v = wd[p];
      wsl[i] = (drow == 0) ? (__bf16)v : (__bf16)(v - (float)(__bf16)v);
    } else {                             // WOE: wo hi/lo, k64-permuted
      int j = i - 79104, orow = j >> 6, k = j & 63, p = kinv(k);
      float v = 0.f;
      if (orow < 3)                  v = wo[p * 3 + orow];
      else if (orow >= 4 && orow < 7) { float ww = wo[p * 3 + orow - 4]; v = ww - (float)(__bf16)ww; }
      wsl[i] = (__bf16)v;
    }
  }
  __syncthreads();   // the only barrier in the kernel

  // ---- load first chunk's x (per-lane; quads redundant, L1 absorbs)
  f32x2 xr[NT][3];
  {
    const float* xp0 = x + (size_t)(blockIdx.x * 512 + pw) * 6;
#pragma unroll
    for (int nt = 0; nt < NT; ++nt) {
      const float* xp = xp0 + (nt * 16 + l16) * 6;
      xr[nt][0] = *(const f32x2*)xp;
      xr[nt][1] = *(const f32x2*)(xp + 2);
      xr[nt][2] = *(const f32x2*)(xp + 4);
    }
  }

  for (int ch = blockIdx.x; ch < NCHUNK; ch += NBLK) {
    const int p0 = ch * 512;

    // ---- build pos/vdir B-frags in registers (k0-2 pos_hi, k3-5 pos_lo,
    //      k6-8 pos_hi, k9-11 vdir_hi, k12-14 vdir_lo, k15=0; quads 2-3 zero)
    bf16x8 pf[NT];
#pragma unroll
    for (int nt = 0; nt < NT; ++nt) {
      float px = xr[nt][0][0], py = xr[nt][0][1], pz = xr[nt][1][0];
      float vx = xr[nt][1][1], vy = xr[nt][2][0], vz = xr[nt][2][1];
      bf16x8 v = zero8();
      if (quad == 0) {
        __bf16 phx = (__bf16)px, phy = (__bf16)py, phz = (__bf16)pz;
        v[0] = phx; v[1] = phy; v[2] = phz;
        v[3] = (__bf16)(px - (float)phx);
        v[4] = (__bf16)(py - (float)phy);
        v[5] = (__bf16)(pz - (float)phz);
        v[6] = phx; v[7] = phy;
      } else if (quad == 1) {
        __bf16 vhx = (__bf16)vx, vhy = (__bf16)vy, vhz = (__bf16)vz;
        v[0] = (__bf16)pz; v[1] = vhx; v[2] = vhy; v[3] = vhz;
        v[4] = (__bf16)(vx - (float)vhx);
        v[5] = (__bf16)(vy - (float)vhy);
        v[6] = (__bf16)(vz - (float)vhz);
        v[7] = (__bf16)0.f;
      }
      pf[nt] = v;
    }

    // ---- prefetch next chunk's x under this chunk's compute
    if (ch + NBLK < NCHUNK) {
      const float* xp0 = x + (size_t)((ch + NBLK) * 512 + pw) * 6;
#pragma unroll
      for (int nt = 0; nt < NT; ++nt) {
        const float* xp = xp0 + (nt * 16 + l16) * 6;
        xr[nt][0] = *(const f32x2*)xp;
        xr[nt][1] = *(const f32x2*)(xp + 2);
        xr[nt][2] = *(const f32x2*)(xp + 4);
      }
    }

    bf16x8 hA[4][NT], hB[4][NT];

    // ---- layer 0: h0 = relu(pos @ w0 + b0), K=32 fixup MFMA from LDS
#pragma unroll
    for (int pr = 0; pr < 4; ++pr) {
      f32x4 acc0[NT], acc1[NT];
      f32x4 bv0 = *(const f32x4*)(b0 + pr * 32 + quad * 4);
      f32x4 bv1 = *(const f32x4*)(b0 + pr * 32 + 16 + quad * 4);
#pragma unroll
      for (int nt = 0; nt < NT; ++nt) { acc0[nt] = bv0; acc1[nt] = bv1; }
      bf16x8 wa = zero8(), wb = zero8();
      if (quad < 2) {
        wa = *(const bf16x8*)(wsl + W0E + (pr * 32 + l16) * 16 + quad * 8);
        wb = *(const bf16x8*)(wsl + W0E + (pr * 32 + 16 + l16) * 16 + quad * 8);
      }
#pragma unroll
      for (int nt = 0; nt < NT; ++nt) {
        acc0[nt] = __builtin_amdgcn_mfma_f32_16x16x32_bf16(wa, pf[nt], acc0[nt], 0, 0, 0);
        acc1[nt] = __builtin_amdgcn_mfma_f32_16x16x32_bf16(wb, pf[nt], acc1[nt], 0, 0, 0);
      }
#pragma unroll
      for (int nt = 0; nt < NT; ++nt) hA[pr][nt] = pack_relu(acc0[nt], acc1[nt]);
    }

    // ---- layers 1..3 (activations never leave registers, no barriers)
    mlayer<4, false>(wsl + W1P, b1, nullptr,   pf, hA, hB, l16, quad);
    mlayer<4, true >(wsl + W2P, b2, wsl + W2E, pf, hB, hA, l16, quad);
    mlayer<4, false>(wsl + W3P, b3, nullptr,   pf, hA, hB, l16, quad);

    // ---- density = relu(h3 @ wd + bd) from LDS WDE
    {
      f32x4 accd[NT];
#pragma unroll
      for (int nt = 0; nt < NT; ++nt) accd[nt] = f32x4{0.f, 0.f, 0.f, 0.f};
      int drow = (l16 < 2) ? l16 : 0;
#pragma unroll
      for (int c = 0; c < 4; ++c) {
        bf16x8 ad = *(const bf16x8*)(wsl + WDE + drow * 128 + c * 32 + quad * 8);
#pragma unroll
        for (int nt = 0; nt < NT; ++nt)
          accd[nt] = __builtin_amdgcn_mfma_f32_16x16x32_bf16(ad, hB[c][nt], accd[nt], 0, 0, 0);
      }
      float bdv = bd[0];
      if (quad == 0) {
#pragma unroll
        for (int nt = 0; nt < NT; ++nt)
          out[(size_t)3 * N_PTS + p0 + pw + nt * 16 + l16] =
              fmaxf(accd[nt][0] + accd[nt][1] + bdv, 0.f);
      }
    }

    // ---- features = relu(h3 @ wf + bf)
    mlayer<4, false>(wsl + WFP, bfv, nullptr, pf, hB, hA, l16, quad);

    // ---- r = relu([feat, vdir] @ wr + br), 64 outputs
    bf16x8 hR[2][NT];
    mlayer<2, true>(wsl + WRP, br, wsl + WRE, pf, hA, hR, l16, quad);

    // ---- rgb = sigmoid(r @ wo + bo) from LDS WOE
    {
      f32x4 acco[NT];
#pragma unroll
      for (int nt = 0; nt < NT; ++nt) acco[nt] = f32x4{0.f, 0.f, 0.f, 0.f};
      int orow = l16 & 7;
#pragma unroll
      for (int c = 0; c < 2; ++c) {
        bf16x8 ao = *(const bf16x8*)(wsl + WOE + orow * 64 + c * 32 + quad * 8);
#pragma unroll
        for (int nt = 0; nt < NT; ++nt)
          acco[nt] = __builtin_amdgcn_mfma_f32_16x16x32_bf16(ao, hR[c][nt], acco[nt], 0, 0, 0);
      }
      float bo0 = bo[0], bo1 = bo[1], bo2 = bo[2];
#pragma unroll
      for (int nt = 0; nt < NT; ++nt) {
        float lo0 = __shfl_xor(acco[nt][0], 16, 64);
        float lo1 = __shfl_xor(acco[nt][1], 16, 64);
        float lo2 = __shfl_xor(acco[nt][2], 16, 64);
        if (quad == 0) {
          size_t o = (size_t)(p0 + pw + nt * 16 + l16) * 3;
          out[o + 0] = 1.f / (1.f + __expf(-(acco[nt][0] + lo0 + bo0)));
          out[o + 1] = 1.f / (1.f + __expf(-(acco[nt][1] + lo1 + bo1)));
          out[o + 2] = 1.f / (1.f + __expf(-(acco[nt][2] + lo2 + bo2)));
        }
      }
    }
  }
}

extern "C" void kernel_launch(void* const* d_in, const int* in_sizes, int n_in,
                              void* d_out, int out_size, void* d_ws, size_t ws_size,
                              hipStream_t stream) {
  const float* x  = (const float*)d_in[0];
  const float* w0 = (const float*)d_in[1];
  const float* b0 = (const float*)d_in[2];
  const float* w1 = (const float*)d_in[3];
  const float* b1 = (const float*)d_in[4];
  const float* w2 = (const float*)d_in[5];
  const float* b2 = (const float*)d_in[6];
  const float* w3 = (const float*)d_in[7];
  const float* b3 = (const float*)d_in[8];
  const float* wd = (const float*)d_in[9];
  const float* bd = (const float*)d_in[10];
  const float* wf = (const float*)d_in[11];
  const float* bfv= (const float*)d_in[12];
  const float* wr = (const float*)d_in[13];
  const float* br = (const float*)d_in[14];
  const float* wo = (const float*)d_in[15];
  const float* bo = (const float*)d_in[16];
  float* out = (float*)d_out;

  nerf_kernel<<<NBLK, 512, 0, stream>>>(x, w0, b0, w1, b1, w2, b2, w3, b3,
                                        wd, bd, wf, bfv, wr, br, wo, bo, out);
}

// Round 7
// 210.044 us; speedup vs baseline: 3.8724x; 3.8724x over previous
//
#include <hip/hip_runtime.h>
#include <hip/hip_bf16.h>

#define N_PTS (4096 * 192)
#define NT    4            // point-tiles (of 16) per wave -> 64 points/wave

typedef __bf16 bf16x8 __attribute__((ext_vector_type(8)));
typedef float  f32x4  __attribute__((ext_vector_type(4)));
typedef float  f32x2  __attribute__((ext_vector_type(2)));

// ws layout (bf16 element offsets). Main tiles are [m][k'] with k rows permuted
// by kinv (MFMA C-layout of layer l == B-frag layout of layer l+1) AND
// column-chunk XOR-swizzled (16B slot s -> s ^ (m&15)) so a LINEAR
// global_load_lds copy produces a bank-conflict-free LDS image for
// ds_read_b128 at 256B row stride (read applies the same XOR).
#define W1P 0          // 128x128
#define W2P 16384      // 128x128 (rows 0..127 of w2)
#define W3P 32768      // 128x128
#define WFP 49152      // 128x128
#define WRP 65536      // 64x128
#define W0E 73728      // 128x16  fixup vs pos-frag (global-read)
#define W2E 75776      // 128x16
#define WRE 77824      // 64x16
#define WDE 78848      // 2x128   row0 = wd_hi[kinv], row1 = wd_lo[kinv]
#define WOE 79104      // 8x64    rows0-2 = wo_hi ch, rows4-6 = wo_lo ch
#define WMAIN_ELEMS 73728   // contiguous W1..WR span staged to LDS (147,456 B)

__device__ __forceinline__ int kinv(int k) {
  int c = k >> 5, q = (k >> 3) & 3, h = (k >> 2) & 1, r = k & 3;
  return (2 * c + h) * 16 + q * 4 + r;
}

__global__ void prep_kernel(const float* __restrict__ w0, const float* __restrict__ w1,
                            const float* __restrict__ w2, const float* __restrict__ w3,
                            const float* __restrict__ wf, const float* __restrict__ wr,
                            const float* __restrict__ wd, const float* __restrict__ wo,
                            __bf16* __restrict__ ws) {
  int i = blockIdx.x * 256 + threadIdx.x;
  if (i < 65536) {                       // w1,w2,w3,wf main tiles: k-permuted + swizzled
    int t = i >> 14, j = i & 16383, m = j >> 7, col = j & 127;
    int k = (((col >> 3) ^ (m & 15)) << 3) | (col & 7);
    int p = kinv(k);
    const float* w = (t == 0) ? w1 : (t == 1) ? w2 : (t == 2) ? w3 : wf;
    ws[i] = (__bf16)w[p * 128 + m];
  } else if (i < 73728) {                // wr main tile
    int j = i - 65536, m = j >> 7, col = j & 127;
    int k = (((col >> 3) ^ (m & 15)) << 3) | (col & 7);
    ws[i] = (__bf16)wr[kinv(k) * 64 + m];
  } else if (i < 75776) {                // W0E (k-space = pos-frag, no permutation)
    int j = i - 73728, f = j >> 4, k = j & 15; float v = 0.f;
    if (k < 3)      v = w0[k * 128 + f];
    else if (k < 6) v = w0[(k - 3) * 128 + f];
    else if (k < 9) { float w = w0[(k - 6) * 128 + f]; v = w - (float)(__bf16)w; }
    ws[i] = (__bf16)v;
  } else if (i < 77824) {                // W2E
    int j = i - 75776, f = j >> 4, k = j & 15; float v = 0.f;
    if (k < 3)      v = w2[(128 + k) * 128 + f];
    else if (k < 6) v = w2[(128 + k - 3) * 128 + f];
    else if (k < 9) { float w = w2[(128 + k - 6) * 128 + f]; v = w - (float)(__bf16)w; }
    ws[i] = (__bf16)v;
  } else if (i < 78848) {                // WRE
    int j = i - 77824, n = j >> 4, k = j & 15; float v = 0.f;
    if (k >= 9 && k < 15) v = wr[(128 + ((k - 9) % 3)) * 64 + n];
    ws[i] = (__bf16)v;
  } else if (i < 79104) {                // WDE: wd hi/lo, k-permuted
    int j = i - 78848, row = j >> 7, k = j & 127, p = kinv(k);
    float v = wd[p];
    ws[i] = (row == 0) ? (__bf16)v : (__bf16)(v - (float)(__bf16)v);
  } else if (i < 79616) {                // WOE: wo hi/lo, k64-permuted
    int j = i - 79104, row = j >> 6, k = j & 63, p = kinv(k);
    float v = 0.f;
    if (row < 3)                 v = wo[p * 3 + row];
    else if (row >= 4 && row < 7) { float w = wo[p * 3 + row - 4]; v = w - (float)(__bf16)w; }
    ws[i] = (__bf16)v;
  }
}

__device__ __forceinline__ bf16x8 zero8() {
  bf16x8 z;
#pragma unroll
  for (int i = 0; i < 8; ++i) z[i] = (__bf16)0.f;
  return z;
}

__device__ __forceinline__ bf16x8 pack_relu(f32x4 e, f32x4 o) {
  bf16x8 v;
#pragma unroll
  for (int r = 0; r < 4; ++r) {
    v[r]     = (__bf16)fmaxf(e[r], 0.f);
    v[4 + r] = (__bf16)fmaxf(o[r], 0.f);
  }
  return v;
}

// One layer from LDS-resident swizzled weights. K=128, acts in registers.
// All ds_read addresses = lane_off[c] + compile-time immediate.
template <int NPAIR, bool FIX>
__device__ __forceinline__ void mlayer(const __bf16* __restrict__ wlds,
                                       const float* __restrict__ bias,
                                       const __bf16* __restrict__ wext,
                                       const bf16x8 (&pf)[NT],
                                       const bf16x8 (&hin)[4][NT],
                                       bf16x8 (&hout)[NPAIR][NT],
                                       const int (&lane_off)[4],
                                       int l16, int quad) {
#pragma unroll
  for (int pr = 0; pr < NPAIR; ++pr) {
    f32x4 acc0[NT], acc1[NT];
    f32x4 bv0 = *(const f32x4*)(bias + pr * 32 + quad * 4);
    f32x4 bv1 = *(const f32x4*)(bias + pr * 32 + 16 + quad * 4);
#pragma unroll
    for (int nt = 0; nt < NT; ++nt) { acc0[nt] = bv0; acc1[nt] = bv1; }
#pragma unroll
    for (int c = 0; c < 4; ++c) {
      const __bf16* base = wlds + pr * 4096 + lane_off[c];
      bf16x8 a0 = *(const bf16x8*)(base);
      bf16x8 a1 = *(const bf16x8*)(base + 2048);
#pragma unroll
      for (int nt = 0; nt < NT; ++nt) {
        acc0[nt] = __builtin_amdgcn_mfma_f32_16x16x32_bf16(a0, hin[c][nt], acc0[nt], 0, 0, 0);
        acc1[nt] = __builtin_amdgcn_mfma_f32_16x16x32_bf16(a1, hin[c][nt], acc1[nt], 0, 0, 0);
      }
    }
    if constexpr (FIX) {
      bf16x8 a0 = zero8(), a1 = zero8();
      if (quad < 2) {
        a0 = *(const bf16x8*)(wext + (pr * 32 + l16) * 16 + quad * 8);
        a1 = *(const bf16x8*)(wext + (pr * 32 + 16 + l16) * 16 + quad * 8);
      }
#pragma unroll
      for (int nt = 0; nt < NT; ++nt) {
        acc0[nt] = __builtin_amdgcn_mfma_f32_16x16x32_bf16(a0, pf[nt], acc0[nt], 0, 0, 0);
        acc1[nt] = __builtin_amdgcn_mfma_f32_16x16x32_bf16(a1, pf[nt], acc1[nt], 0, 0, 0);
      }
    }
#pragma unroll
    for (int nt = 0; nt < NT; ++nt) hout[pr][nt] = pack_relu(acc0[nt], acc1[nt]);
  }
}

__global__ __launch_bounds__(512)
__attribute__((amdgpu_waves_per_eu(2, 2)))
void nerf_kernel(
    const float* __restrict__ x,
    const float* __restrict__ b0, const float* __restrict__ b1,
    const float* __restrict__ b2, const float* __restrict__ b3,
    const float* __restrict__ bd, const float* __restrict__ bfv,
    const float* __restrict__ br, const float* __restrict__ bo,
    const __bf16* __restrict__ ws,
    float* __restrict__ out) {
  __shared__ __align__(16) __bf16 wsl[WMAIN_ELEMS];   // 147,456 B: W1..WR

  const int tid  = threadIdx.x;
  const int wv   = tid >> 6;
  const int lane = tid & 63;
  const int quad = lane >> 4;
  const int l16  = lane & 15;
  const int p0   = blockIdx.x * 512;
  const int pw   = wv * 64;

  // ---- per-lane x loads first (12 dwords; ahead of staging in vmcnt order)
  f32x2 xr[NT][3];
  {
    const float* xp0 = x + (size_t)(p0 + pw) * 6;
#pragma unroll
    for (int nt = 0; nt < NT; ++nt) {
      const float* xp = xp0 + (nt * 16 + l16) * 6;
      xr[nt][0] = *(const f32x2*)xp;
      xr[nt][1] = *(const f32x2*)(xp + 2);
      xr[nt][2] = *(const f32x2*)(xp + 4);
    }
  }
  // ---- l0 fixup A-frags (global, before staging)
  bf16x8 w0a[4], w0b[4];
#pragma unroll
  for (int pr = 0; pr < 4; ++pr) {
    w0a[pr] = zero8(); w0b[pr] = zero8();
    if (quad < 2) {
      w0a[pr] = *(const bf16x8*)(ws + W0E + (pr * 32 + l16) * 16 + quad * 8);
      w0b[pr] = *(const bf16x8*)(ws + W0E + (pr * 32 + 16 + l16) * 16 + quad * 8);
    }
  }

  // ---- stage ALL main weight tiles (144 KiB, contiguous, 18 rounds)
  {
    const char* g = (const char*)ws;
    char* l = (char*)wsl;
#pragma unroll
    for (int r = 0; r < 147456; r += 8192) {
      const char* src = g + r + wv * 1024 + lane * 16;
      char* dst = l + r + wv * 1024;                    // wave-uniform base
      __builtin_amdgcn_global_load_lds(
          (const __attribute__((address_space(1))) void*)src,
          (__attribute__((address_space(3))) void*)dst, 16, 0, 0);
    }
  }

  // ---- swizzled lane offsets, computed once (all ds_reads = base + imm)
  int lane_off[4];
#pragma unroll
  for (int c = 0; c < 4; ++c)
    lane_off[c] = l16 * 128 + ((((c * 4 + quad) ^ l16)) << 3);

  // ---- pos/vdir B-frags in registers (k0-2 pos_hi, k3-5 pos_lo, k6-8 pos_hi,
  //      k9-11 vdir_hi, k12-14 vdir_lo, k15=0; quads 2-3 zero)
  bf16x8 pf[NT];
#pragma unroll
  for (int nt = 0; nt < NT; ++nt) {
    float px = xr[nt][0][0], py = xr[nt][0][1], pz = xr[nt][1][0];
    float vx = xr[nt][1][1], vy = xr[nt][2][0], vz = xr[nt][2][1];
    bf16x8 v = zero8();
    if (quad == 0) {
      __bf16 phx = (__bf16)px, phy = (__bf16)py, phz = (__bf16)pz;
      v[0] = phx; v[1] = phy; v[2] = phz;
      v[3] = (__bf16)(px - (float)phx);
      v[4] = (__bf16)(py - (float)phy);
      v[5] = (__bf16)(pz - (float)phz);
      v[6] = phx; v[7] = phy;
    } else if (quad == 1) {
      __bf16 vhx = (__bf16)vx, vhy = (__bf16)vy, vhz = (__bf16)vz;
      v[0] = (__bf16)pz; v[1] = vhx; v[2] = vhy; v[3] = vhz;
      v[4] = (__bf16)(vx - (float)vhx);
      v[5] = (__bf16)(vy - (float)vhy);
      v[6] = (__bf16)(vz - (float)vhz);
      v[7] = (__bf16)0.f;
    }
    pf[nt] = v;
  }

  bf16x8 hA[4][NT], hB[4][NT];

  // ---- layer 0: h0 = relu(pos @ w0 + b0) — register-only, hides staging
#pragma unroll
  for (int pr = 0; pr < 4; ++pr) {
    f32x4 acc0[NT], acc1[NT];
    f32x4 bv0 = *(const f32x4*)(b0 + pr * 32 + quad * 4);
    f32x4 bv1 = *(const f32x4*)(b0 + pr * 32 + 16 + quad * 4);
#pragma unroll
    for (int nt = 0; nt < NT; ++nt) { acc0[nt] = bv0; acc1[nt] = bv1; }
#pragma unroll
    for (int nt = 0; nt < NT; ++nt) {
      acc0[nt] = __builtin_amdgcn_mfma_f32_16x16x32_bf16(w0a[pr], pf[nt], acc0[nt], 0, 0, 0);
      acc1[nt] = __builtin_amdgcn_mfma_f32_16x16x32_bf16(w0b[pr], pf[nt], acc1[nt], 0, 0, 0);
    }
#pragma unroll
    for (int nt = 0; nt < NT; ++nt) hA[pr][nt] = pack_relu(acc0[nt], acc1[nt]);
  }
  __syncthreads();   // staging visible — the ONLY barrier; waves free-run after

  // ---- layers 1..3 (no barriers; waves desync -> MFMA/VALU overlap)
  mlayer<4, false>(wsl + W1P, b1, nullptr,   pf, hA, hB, lane_off, l16, quad);
  mlayer<4, true >(wsl + W2P, b2, ws + W2E,  pf, hB, hA, lane_off, l16, quad);
  mlayer<4, false>(wsl + W3P, b3, nullptr,   pf, hA, hB, lane_off, l16, quad);

  // ---- density = relu(h3 @ wd + bd) from global WDE
  {
    f32x4 accd[NT];
#pragma unroll
    for (int nt = 0; nt < NT; ++nt) accd[nt] = f32x4{0.f, 0.f, 0.f, 0.f};
    int drow = (l16 < 2) ? l16 : 0;
#pragma unroll
    for (int c = 0; c < 4; ++c) {
      bf16x8 ad = *(const bf16x8*)(ws + WDE + drow * 128 + c * 32 + quad * 8);
#pragma unroll
      for (int nt = 0; nt < NT; ++nt)
        accd[nt] = __builtin_amdgcn_mfma_f32_16x16x32_bf16(ad, hB[c][nt], accd[nt], 0, 0, 0);
    }
    float bdv = bd[0];
    if (quad == 0) {
#pragma unroll
      for (int nt = 0; nt < NT; ++nt)
        out[(size_t)3 * N_PTS + p0 + pw + nt * 16 + l16] =
            fmaxf(accd[nt][0] + accd[nt][1] + bdv, 0.f);
    }
  }

  // ---- features = relu(h3 @ wf + bf)
  mlayer<4, false>(wsl + WFP, bfv, nullptr, pf, hB, hA, lane_off, l16, quad);

  // ---- r = relu([feat, vdir] @ wr + br), 64 outputs
  bf16x8 hR[2][NT];
  mlayer<2, true>(wsl + WRP, br, ws + WRE, pf, hA, hR, lane_off, l16, quad);

  // ---- rgb = sigmoid(r @ wo + bo) from global WOE
  {
    f32x4 acco[NT];
#pragma unroll
    for (int nt = 0; nt < NT; ++nt) acco[nt] = f32x4{0.f, 0.f, 0.f, 0.f};
    int orow = l16 & 7;
#pragma unroll
    for (int c = 0; c < 2; ++c) {
      bf16x8 ao = *(const bf16x8*)(ws + WOE + orow * 64 + c * 32 + quad * 8);
#pragma unroll
      for (int nt = 0; nt < NT; ++nt)
        acco[nt] = __builtin_amdgcn_mfma_f32_16x16x32_bf16(ao, hR[c][nt], acco[nt], 0, 0, 0);
    }
    float bo0 = bo[0], bo1 = bo[1], bo2 = bo[2];
#pragma unroll
    for (int nt = 0; nt < NT; ++nt) {
      float lo0 = __shfl_xor(acco[nt][0], 16, 64);
      float lo1 = __shfl_xor(acco[nt][1], 16, 64);
      float lo2 = __shfl_xor(acco[nt][2], 16, 64);
      if (quad == 0) {
        size_t o = (size_t)(p0 + pw + nt * 16 + l16) * 3;
        out[o + 0] = 1.f / (1.f + __expf(-(acco[nt][0] + lo0 + bo0)));
        out[o + 1] = 1.f / (1.f + __expf(-(acco[nt][1] + lo1 + bo1)));
        out[o + 2] = 1.f / (1.f + __expf(-(acco[nt][2] + lo2 + bo2)));
      }
    }
  }
}

extern "C" void kernel_launch(void* const* d_in, const int* in_sizes, int n_in,
                              void* d_out, int out_size, void* d_ws, size_t ws_size,
                              hipStream_t stream) {
  const float* x  = (const float*)d_in[0];
  const float* w0 = (const float*)d_in[1];
  const float* b0 = (const float*)d_in[2];
  const float* w1 = (const float*)d_in[3];
  const float* b1 = (const float*)d_in[4];
  const float* w2 = (const float*)d_in[5];
  const float* b2 = (const float*)d_in[6];
  const float* w3 = (const float*)d_in[7];
  const float* b3 = (const float*)d_in[8];
  const float* wd = (const float*)d_in[9];
  const float* bd = (const float*)d_in[10];
  const float* wf = (const float*)d_in[11];
  const float* bfv= (const float*)d_in[12];
  const float* wr = (const float*)d_in[13];
  const float* br = (const float*)d_in[14];
  const float* wo = (const float*)d_in[15];
  const float* bo = (const float*)d_in[16];
  __bf16* ws = (__bf16*)d_ws;
  float* out = (float*)d_out;

  prep_kernel<<<311, 256, 0, stream>>>(w0, w1, w2, w3, wf, wr, wd, wo, ws);
  nerf_kernel<<<N_PTS / 512, 512, 0, stream>>>(x, b0, b1, b2, b3, bd, bfv, br, bo, ws, out);
}